// Round 1
// baseline (33733.344 us; speedup 1.0000x reference)
//
#include <hip/hip_runtime.h>
#include <math.h>

#define LR_C 0.1f
#define WINDOW_C 10
#define NH 512
#define NBLK 8   // 512 units / 64 lanes
#define WAVE 64

// Kernel 1: per-t reward prediction error + packed scan operands.
// pack[t] = {x0, x1, LR*r*x0, LR*r*x1}
__global__ void prep_kernel(const float* __restrict__ X,
                            const float* __restrict__ rewards,
                            float4* __restrict__ pack, int T) {
    int t = blockIdx.x * blockDim.x + threadIdx.x;
    if (t >= T) return;
    int lo = t - (WINDOW_C - 1); if (lo < 0) lo = 0;
    float s = 0.0f;
    for (int k = lo; k <= t; ++k) s += rewards[k];
    float cnt = (float)(t - lo + 1);
    float r = rewards[t] - s / cnt;
    float c = LR_C * r;
    float x0 = X[2 * t];
    float x1 = X[2 * t + 1];
    pack[t] = make_float4(x0, x1, c * x0, c * x1);
}

// Kernel 2: sequential scan. Block b owns hidden units [b*64, b*64+64).
// One wave per block: shuffle-only reduction, no LDS, no barriers.
__global__ __launch_bounds__(WAVE) void scan_kernel(const float* __restrict__ Winit,
                                                    const float4* __restrict__ pack,
                                                    float* __restrict__ partial, int T) {
    const int lane = threadIdx.x;
    const int b = blockIdx.x;
    const int i = b * WAVE + lane;
    float w0 = Winit[2 * i];
    float w1 = Winit[2 * i + 1];
    float* __restrict__ out = partial + (size_t)b * T;

    for (int t = 0; t < T; ++t) {
        float4 p = pack[t];                      // wave-uniform broadcast load
        float z = fmaf(w1, p.y, w0 * p.x);       // W[i]·x
        float h = 1.0f / (1.0f + expf(-z));      // sigmoid (precise expf)
        w0 = fmaf(h, p.z, w0);                   // w += (LR*r*x) * h
        w1 = fmaf(h, p.w, w1);
        float s = h;                             // wave sum (off critical path)
        #pragma unroll
        for (int m = 1; m < WAVE; m <<= 1) s += __shfl_xor(s, m, WAVE);
        if (lane == 0) out[t] = s;
    }
}

// Kernel 3: combine 8 per-block partial sums -> mean trajectory.
__global__ void final_kernel(const float* __restrict__ partial,
                             float* __restrict__ out, int T) {
    int t = blockIdx.x * blockDim.x + threadIdx.x;
    if (t >= T) return;
    float s = 0.0f;
    #pragma unroll
    for (int b = 0; b < NBLK; ++b) s += partial[(size_t)b * T + t];
    out[t] = s * (1.0f / (float)NH);
}

extern "C" void kernel_launch(void* const* d_in, const int* in_sizes, int n_in,
                              void* d_out, int out_size, void* d_ws, size_t ws_size,
                              hipStream_t stream) {
    const float* X       = (const float*)d_in[0];
    const float* rewards = (const float*)d_in[1];
    const float* Winit   = (const float*)d_in[2];
    float* out = (float*)d_out;
    const int T = in_sizes[1];

    float4* pack   = (float4*)d_ws;
    float* partial = (float*)((char*)d_ws + sizeof(float4) * (size_t)T);
    // ws usage: 16*T + 4*8*T = 48*T bytes (~4.8 MB for T=100000)

    int threads = 256;
    int blocks = (T + threads - 1) / threads;
    prep_kernel<<<blocks, threads, 0, stream>>>(X, rewards, pack, T);
    scan_kernel<<<NBLK, WAVE, 0, stream>>>(Winit, pack, partial, T);
    final_kernel<<<blocks, threads, 0, stream>>>(partial, out, T);
}

// Round 2
// 4092.478 us; speedup vs baseline: 8.2428x; 8.2428x over previous
//
#include <hip/hip_runtime.h>
#include <math.h>

#define LR_C 0.1f
#define WINDOW_C 10
#define NH 512
#define NBLK 8   // 512 units / 64 lanes
#define WAVE 64
#define ALPHA (-1.44269504088896340736f)  // -log2(e)

// pack[t] = {x0, x1, ALPHA*LR*r*x0, ALPHA*LR*r*x1}
// Scan carries w' = ALPHA*w, so  y = w'·x,  e^{-z} = exp2(y),
// h = 1/(1+exp2(y)),  w' += h * (ALPHA*LR*r*x).
__global__ void prep_kernel(const float* __restrict__ X,
                            const float* __restrict__ rewards,
                            float4* __restrict__ pack, int T) {
    int t = blockIdx.x * blockDim.x + threadIdx.x;
    if (t >= T) return;
    int lo = t - (WINDOW_C - 1); if (lo < 0) lo = 0;
    float s = 0.0f;
    for (int k = lo; k <= t; ++k) s += rewards[k];
    float cnt = (float)(t - lo + 1);
    float r = rewards[t] - s / cnt;
    float c = ALPHA * LR_C * r;
    float x0 = X[2 * t];
    float x1 = X[2 * t + 1];
    pack[t] = make_float4(x0, x1, c * x0, c * x1);
}

// MODE 0: store every lane's h to hall[t*512 + unit]  (no cross-lane ops)
// MODE 1: in-wave full reduction, lane0 stores partial[b*T + t]
template <int MODE>
__global__ __launch_bounds__(WAVE) void scan_kernel(const float* __restrict__ Winit,
                                                    const float4* __restrict__ pack,
                                                    float* __restrict__ sink, int T) {
    const int lane = threadIdx.x;
    const int b = blockIdx.x;
    const int i = b * WAVE + lane;
    float w0 = ALPHA * Winit[2 * i];
    float w1 = ALPHA * Winit[2 * i + 1];

    float* __restrict__ hall  = sink + (size_t)i;          // MODE 0: + t*512
    float* __restrict__ partq = sink + (size_t)b * T;      // MODE 1: + t

    float4 pA[8], pB[8];
    float hh[8];
    const int T16 = T & ~15;

#define BODY(P, TT)                                                          \
    {                                                                        \
        _Pragma("unroll")                                                    \
        for (int j = 0; j < 8; ++j) {                                        \
            float y = fmaf(w1, P[j].y, w0 * P[j].x);                         \
            float e = __builtin_amdgcn_exp2f(y);                             \
            float h = __builtin_amdgcn_rcpf(1.0f + e);                       \
            w0 = fmaf(h, P[j].z, w0);                                        \
            w1 = fmaf(h, P[j].w, w1);                                        \
            hh[j] = h;                                                       \
        }                                                                    \
        if (MODE == 0) {                                                     \
            _Pragma("unroll")                                                \
            for (int j = 0; j < 8; ++j)                                      \
                hall[(size_t)((TT) + j) * NH] = hh[j];                       \
        } else {                                                             \
            _Pragma("unroll")                                                \
            for (int j = 0; j < 8; ++j) {                                    \
                float s = hh[j];                                             \
                _Pragma("unroll")                                            \
                for (int m = 1; m < WAVE; m <<= 1) s += __shfl_xor(s, m, WAVE); \
                hh[j] = s;                                                   \
            }                                                                \
            if (lane == 0) {                                                 \
                *(float4*)(partq + (TT))     = make_float4(hh[0], hh[1], hh[2], hh[3]); \
                *(float4*)(partq + (TT) + 4) = make_float4(hh[4], hh[5], hh[6], hh[7]); \
            }                                                                \
        }                                                                    \
    }

    if (T16 >= 16) {
        #pragma unroll
        for (int j = 0; j < 8; ++j) pA[j] = pack[j];
    }
    for (int t0 = 0; t0 < T16; t0 += 16) {
        #pragma unroll
        for (int j = 0; j < 8; ++j) pB[j] = pack[t0 + 8 + j];
        BODY(pA, t0)
        if (t0 + 16 < T16) {
            #pragma unroll
            for (int j = 0; j < 8; ++j) pA[j] = pack[t0 + 16 + j];
        }
        BODY(pB, t0 + 8)
    }
    // tail (T not multiple of 16)
    for (int t = T16; t < T; ++t) {
        float4 p = pack[t];
        float y = fmaf(w1, p.y, w0 * p.x);
        float e = __builtin_amdgcn_exp2f(y);
        float h = __builtin_amdgcn_rcpf(1.0f + e);
        w0 = fmaf(h, p.z, w0);
        w1 = fmaf(h, p.w, w1);
        if (MODE == 0) {
            hall[(size_t)t * NH] = h;
        } else {
            float s = h;
            #pragma unroll
            for (int m = 1; m < WAVE; m <<= 1) s += __shfl_xor(s, m, WAVE);
            if (lane == 0) partq[t] = s;
        }
    }
#undef BODY
}

// MODE 0 finisher: one block per t, 256 threads, sum 512 floats.
__global__ __launch_bounds__(256) void final_hall(const float* __restrict__ hall,
                                                  float* __restrict__ out, int T) {
    int t = blockIdx.x;
    const float2* p = (const float2*)(hall + (size_t)t * NH);
    int tid = threadIdx.x;
    float2 v = p[tid];
    float s = v.x + v.y;
    #pragma unroll
    for (int m = 1; m < WAVE; m <<= 1) s += __shfl_xor(s, m, WAVE);
    __shared__ float ls[4];
    if ((tid & 63) == 0) ls[tid >> 6] = s;
    __syncthreads();
    if (tid == 0) out[t] = (ls[0] + ls[1] + ls[2] + ls[3]) * (1.0f / (float)NH);
}

// MODE 1 finisher: sum the 8 per-block rows.
__global__ void final_part(const float* __restrict__ partial,
                           float* __restrict__ out, int T) {
    int t = blockIdx.x * blockDim.x + threadIdx.x;
    if (t >= T) return;
    float s = 0.0f;
    #pragma unroll
    for (int b = 0; b < NBLK; ++b) s += partial[(size_t)b * T + t];
    out[t] = s * (1.0f / (float)NH);
}

extern "C" void kernel_launch(void* const* d_in, const int* in_sizes, int n_in,
                              void* d_out, int out_size, void* d_ws, size_t ws_size,
                              hipStream_t stream) {
    const float* X       = (const float*)d_in[0];
    const float* rewards = (const float*)d_in[1];
    const float* Winit   = (const float*)d_in[2];
    float* out = (float*)d_out;
    const int T = in_sizes[1];

    float4* pack = (float4*)d_ws;
    float* sink  = (float*)((char*)d_ws + sizeof(float4) * (size_t)T);

    const size_t needA = 16ull * T + 4ull * NH * T;  // pack + hall (~206 MB @ T=1e5)

    int threads = 256;
    int blocks = (T + threads - 1) / threads;
    prep_kernel<<<blocks, threads, 0, stream>>>(X, rewards, pack, T);

    if (ws_size >= needA) {
        scan_kernel<0><<<NBLK, WAVE, 0, stream>>>(Winit, pack, sink, T);
        final_hall<<<T, 256, 0, stream>>>(sink, out, T);
    } else {
        scan_kernel<1><<<NBLK, WAVE, 0, stream>>>(Winit, pack, sink, T);
        final_part<<<blocks, threads, 0, stream>>>(sink, out, T);
    }
}